// Round 1
// baseline (105.201 us; speedup 1.0000x reference)
//
#include <hip/hip_runtime.h>

// Problem constants
#define NB   4096   // B
#define ND   256    // D
#define N2B  8192   // 2B
#define INV_T 2.0f  // 1/TEMP, TEMP=0.5
#define NBAND 64    // 8192 / 128 row-bands
#define NTRI  2080  // 64*65/2 triangular band pairs

typedef __attribute__((ext_vector_type(8))) short bf16x8;
typedef __attribute__((ext_vector_type(4))) float f32x4;

__device__ __forceinline__ void gload_lds16(const void* g, void* l) {
  __builtin_amdgcn_global_load_lds(
      (const __attribute__((address_space(1))) void*)g,
      (__attribute__((address_space(3))) void*)l, 16, 0, 0);
}

// fp32 -> bf16 (RNE) as raw bits
__device__ __forceinline__ unsigned short f2b(float f) {
  unsigned int u = __float_as_uint(f);
  u = (u + 0x7fffu + ((u >> 16) & 1u)) >> 16;
  return (unsigned short)u;
}
__device__ __forceinline__ float b2f(unsigned short h) {
  return __uint_as_float(((unsigned int)h) << 16);
}

// Kernel A: L2-normalize rows of [x_i; x_j] -> Z (bf16 bits).
//   diagE[zrow] = exp(diag/T)   (self term, subtracted in k_final)
//   pos[r] = dot(z_i[r], z_j[r]) (LDS exchange between i- and j-waves)
// Block 0 zero-inits lossAcc and ticket.
__global__ __launch_bounds__(256) void k_normalize(
    const float* __restrict__ xi, const float* __restrict__ xj,
    unsigned short* __restrict__ Z, float* __restrict__ diagE,
    float* __restrict__ pos, float* __restrict__ lossAcc,
    unsigned int* __restrict__ ticket) {
  __shared__ float sh[2][256];
  if (blockIdx.x == 0 && threadIdx.x == 0) { *lossAcc = 0.0f; *ticket = 0u; }
  int wave = threadIdx.x >> 6, lane = threadIdx.x & 63;
  int r = (int)blockIdx.x * 2 + (wave & 1);  // row in [0, NB)
  bool isJ = wave >= 2;
  const float* src = (isJ ? xj : xi) + (size_t)r * ND;
  int zrow = r + (isJ ? NB : 0);

  float4 v = *(const float4*)(src + lane * 4);
  float ss = v.x * v.x + v.y * v.y + v.z * v.z + v.w * v.w;
#pragma unroll
  for (int m = 1; m < 64; m <<= 1) ss += __shfl_xor(ss, m, 64);
  float scale = 1.0f / fmaxf(sqrtf(ss), 1e-12f);
  unsigned short h0 = f2b(v.x * scale), h1 = f2b(v.y * scale);
  unsigned short h2 = f2b(v.z * scale), h3 = f2b(v.w * scale);
  ushort4 st; st.x = h0; st.y = h1; st.z = h2; st.w = h3;
  *(ushort4*)(Z + (size_t)zrow * ND + lane * 4) = st;

  float f0 = b2f(h0), f1 = b2f(h1), f2 = b2f(h2), f3 = b2f(h3);
  float d = f0 * f0 + f1 * f1 + f2 * f2 + f3 * f3;
#pragma unroll
  for (int m = 1; m < 64; m <<= 1) d += __shfl_xor(d, m, 64);
  if (lane == 0) diagE[zrow] = __expf(d * INV_T);

  if (isJ) {
    float* s = sh[wave & 1] + lane * 4;
    s[0] = f0; s[1] = f1; s[2] = f2; s[3] = f3;
  }
  __syncthreads();
  if (!isJ) {
    const float* s = sh[wave] + lane * 4;
    float p = f0 * s[0] + f1 * s[1] + f2 * s[2] + f3 * s[3];
#pragma unroll
    for (int m = 1; m < 64; m <<= 1) p += __shfl_xor(p, m, 64);
    if (lane == 0) pos[r] = p;
  }
}

// Kernel B: SYMMETRIC triangular band GEMM + fused exp / dual reduction.
// sim = Z Z^T is symmetric; only band pairs (I,J), I<=J (2080 blocks of
// 128x128 output, full K=256) are computed. Each block writes:
//   row-partials  P[r in band I][J]  (sum over its 128 cols)
//   col-partials  P[c in band J][I]  (sum over its 128 rows; skipped if I==J
//   -- within-band transpose contribution is already in the row sums)
// Every P slot is written exactly once -> no atomics, no zero-init.
// A (wave's 32 rows, full K) lives in registers the whole block; B-band is
// staged ONCE per block into 64 KiB XOR-chunk-swizzled LDS. One barrier
// between stage and compute (vs 32 in the old streaming version).
__global__ __launch_bounds__(256, 2) void k_sym(
    const unsigned short* __restrict__ Z, float* __restrict__ P) {
  __shared__ alignas(16) unsigned short Bs[128 * ND];  // 64 KiB

  int tid = threadIdx.x;
  int wave = tid >> 6, lane = tid & 63;
  int quad = lane >> 4, c16 = lane & 15;

  // XCD-contiguous triangular remap (2080 = 8 * 260, bijective)
  int t = (int)blockIdx.x;
  t = (t & 7) * (NTRI / 8) + (t >> 3);
  // decode t -> (I, J), 0 <= I <= J < 64;  S(I) = 64I - I(I-1)/2
  int I = (int)((129.0f - sqrtf(16641.0f - 8.0f * (float)t)) * 0.5f);
  while (64 * (I + 1) - ((I + 1) * I) / 2 <= t) ++I;
  while (64 * I - (I * (I - 1)) / 2 > t) --I;
  int J = I + (t - (64 * I - (I * (I - 1)) / 2));
  bool diag = (I == J);

  int rowA = I * 128, rowB = J * 128;

  // Stage B-band (128 rows x K=256 bf16) -> LDS. Row = 32 chunks of 16B;
  // global chunk gc lands in slot gc ^ (row&31)  (involution, so the read
  // side applies the same XOR). Wave-uniform LDS base, lane-swizzled src.
  int lr1 = lane >> 5, cs = lane & 31;
#pragma unroll
  for (int j = 0; j < 16; ++j) {
    int r0 = wave * 32 + j * 2;  // wave-uniform base row (2 rows / call)
    int row = r0 + lr1;
    int gc = cs ^ (row & 31);
    gload_lds16(Z + (size_t)(rowB + row) * ND + gc * 8, &Bs[r0 * ND]);
  }

  // A fragments in registers: wave owns rows rowA + wave*32 .. +31
  bf16x8 afr[2][8];
  int wrow = rowA + wave * 32;
#pragma unroll
  for (int rg = 0; rg < 2; ++rg)
#pragma unroll
    for (int kk = 0; kk < 8; ++kk)
      afr[rg][kk] = *(const bf16x8*)(Z + (size_t)(wrow + rg * 16 + c16) * ND +
                                     kk * 32 + quad * 8);

  asm volatile("s_waitcnt vmcnt(0)" ::: "memory");
  __syncthreads();

  // 128 MFMA per wave over the 32x128 output sub-tile
  f32x4 acc[2][8] = {};
  __builtin_amdgcn_s_setprio(1);
#pragma unroll
  for (int kk = 0; kk < 8; ++kk) {
    bf16x8 bfr[8];
#pragma unroll
    for (int ni = 0; ni < 8; ++ni) {
      int row = ni * 16 + c16;
      int slot = (kk * 4 + quad) ^ (row & 31);
      bfr[ni] = *(const bf16x8*)&Bs[row * ND + slot * 8];
    }
#pragma unroll
    for (int rg = 0; rg < 2; ++rg)
#pragma unroll
      for (int ni = 0; ni < 8; ++ni)
        acc[rg][ni] = __builtin_amdgcn_mfma_f32_16x16x32_bf16(
            afr[rg][kk], bfr[ni], acc[rg][ni], 0, 0, 0);
  }
  __builtin_amdgcn_s_setprio(0);

  // fused exp; accumulate row partials (over cols) and col partials (rows)
  // C/D layout: out_row = quad*4 + r (within frag), out_col = ni*16 + c16
  float rs[2][4];
  float csum[8];
#pragma unroll
  for (int ni = 0; ni < 8; ++ni) csum[ni] = 0.0f;
#pragma unroll
  for (int rg = 0; rg < 2; ++rg)
#pragma unroll
    for (int r = 0; r < 4; ++r) rs[rg][r] = 0.0f;

#pragma unroll
  for (int rg = 0; rg < 2; ++rg)
#pragma unroll
    for (int ni = 0; ni < 8; ++ni)
#pragma unroll
      for (int r = 0; r < 4; ++r) {
        float e = __expf(acc[rg][ni][r] * INV_T);
        rs[rg][r] += e;
        csum[ni] += e;
      }

  // row partials: reduce across c16 (the 16 cols of each frag)
#pragma unroll
  for (int m = 1; m <= 8; m <<= 1)
#pragma unroll
    for (int rg = 0; rg < 2; ++rg)
#pragma unroll
      for (int r = 0; r < 4; ++r)
        rs[rg][r] += __shfl_xor(rs[rg][r], m, 64);

#pragma unroll
  for (int rg = 0; rg < 2; ++rg)
#pragma unroll
    for (int r = 0; r < 4; ++r)
      if (c16 == rg * 4 + r) {
        int row = wrow + rg * 16 + quad * 4 + r;
        P[(size_t)row * NBAND + J] = rs[rg][r];
      }

  if (!diag) {
    // col partials: reduce across quad (the 16 rows of each frag pair)
#pragma unroll
    for (int ni = 0; ni < 8; ++ni) {
      csum[ni] += __shfl_xor(csum[ni], 16, 64);
      csum[ni] += __shfl_xor(csum[ni], 32, 64);
    }
    __syncthreads();  // all waves done reading Bs -> safe to reuse as colred
    float* colred = (float*)Bs;  // [4][128]
    if (lane < 16) {
#pragma unroll
      for (int ni = 0; ni < 8; ++ni)
        colred[wave * 128 + ni * 16 + lane] = csum[ni];
    }
    __syncthreads();
    if (tid < 128) {
      float v = colred[tid] + colred[128 + tid] + colred[256 + tid] +
                colred[384 + tid];
      P[(size_t)(rowB + tid) * NBAND + I] = v;
    }
  }
}

// Kernel C: 32 blocks x 256 rows. rowsum[r] = sum_{q<64} P[r][q] - diagE[r];
// term = log(rowsum) - pos[r%B]/T. Block-reduce -> one atomicAdd per block;
// ticketed last block writes out = lossAcc / 2B.
__global__ __launch_bounds__(256) void k_final(
    const float* __restrict__ P, const float* __restrict__ diagE,
    const float* __restrict__ pos, float* __restrict__ lossAcc,
    unsigned int* __restrict__ ticket, float* __restrict__ out) {
  __shared__ float red[4];
  int tid = threadIdx.x;
  int wave = tid >> 6, lane = tid & 63;
  int row = (int)blockIdx.x * 256 + tid;

  const float4* Pr = (const float4*)(P + (size_t)row * NBAND);
  float s = 0.0f;
#pragma unroll
  for (int q = 0; q < 16; ++q) {
    float4 a = Pr[q];
    s += (a.x + a.y) + (a.z + a.w);
  }
  s -= diagE[row];
  float term = __logf(s) - INV_T * pos[row & (NB - 1)];
#pragma unroll
  for (int m = 1; m < 64; m <<= 1) term += __shfl_xor(term, m, 64);
  if (lane == 0) red[wave] = term;
  __syncthreads();
  if (tid == 0) {
    float bs = red[0] + red[1] + red[2] + red[3];
    atomicAdd(lossAcc, bs);
    __threadfence();
    unsigned int old = atomicAdd(ticket, 1u);
    if (old == 31u) {
      float v = atomicAdd(lossAcc, 0.0f);  // atomic read after all adds
      out[0] = v * (1.0f / (float)N2B);
    }
  }
}

extern "C" void kernel_launch(void* const* d_in, const int* in_sizes, int n_in,
                              void* d_out, int out_size, void* d_ws,
                              size_t ws_size, hipStream_t stream) {
  const float* xi = (const float*)d_in[0];
  const float* xj = (const float*)d_in[1];
  float* out = (float*)d_out;
  char* ws = (char*)d_ws;
  unsigned short* Z = (unsigned short*)ws;           // 4 MiB
  float* P = (float*)(ws + (4u << 20));              // 8192*64*4 = 2 MiB
  float* pos = (float*)(ws + (6u << 20));            // 16 KiB
  float* diagE = (float*)(ws + (6u << 20) + 65536);  // 32 KiB
  float* lossAcc = (float*)(ws + (6u << 20) + 131072);
  unsigned int* ticket = (unsigned int*)(ws + (6u << 20) + 131072 + 64);

  k_normalize<<<dim3(NB / 2), dim3(256), 0, stream>>>(xi, xj, Z, diagE, pos,
                                                      lossAcc, ticket);
  k_sym<<<dim3(NTRI), dim3(256), 0, stream>>>(Z, P);
  k_final<<<dim3(32), dim3(256), 0, stream>>>(P, diagE, pos, lossAcc, ticket,
                                              out);
}